// Round 1
// baseline (2719.927 us; speedup 1.0000x reference)
//
#include <hip/hip_runtime.h>

#define H64 64
#define SEQL 4096
#define NB 64
#define TOK 32

// ---------------------------------------------------------------------------
// Encoder: embed -> FF(relu) -> residual -> LayerNorm -> k (l2norm), v, q, qlast
// One block = 32 tokens (never straddles a batch: 4096 % 32 == 0).
// ---------------------------------------------------------------------------
__global__ __launch_bounds__(256) void encoder_kernel(
    const int* __restrict__ x, const float* __restrict__ embed,
    const float* __restrict__ W1, const float* __restrict__ b1,
    const float* __restrict__ W2, const float* __restrict__ b2,
    const float* __restrict__ ln_g, const float* __restrict__ ln_b,
    const float* __restrict__ Wk, const float* __restrict__ Wv,
    const float* __restrict__ Wq, const float* __restrict__ Wattn,
    float* __restrict__ ks, float* __restrict__ vs,
    float* __restrict__ qbuf, float* __restrict__ qlast)
{
    __shared__ __align__(16) float sW[128 * 65];   // W1T[64][129] / W2T[128][65] / WT[64][65]
    __shared__ __align__(16) float sZT[64 * 36];   // h / hidden, transposed [i][t]
    __shared__ __align__(16) float sFT[128 * 36];  // ff1, transposed [p][t]
    __shared__ float sb1[128], sb2[64], sg[64], sbt[64];

    const int tid = threadIdx.x;
    const size_t g0 = (size_t)blockIdx.x * TOK;
    const int b = (int)(g0 >> 12);
    const int l0 = (int)(g0 & (SEQL - 1));

    if (tid < 128) sb1[tid] = b1[tid];
    else if (tid < 192) sb2[tid - 128] = b2[tid - 128];
    else { sg[tid - 192] = ln_g[tid - 192]; sbt[tid - 192] = ln_b[tid - 192]; }

    // h
    for (int idx = tid; idx < TOK * 64; idx += 256) {
        int t = idx >> 6, i = idx & 63;
        sZT[i * 36 + t] = embed[(size_t)x[g0 + t] * 64 + i];
    }
    // W1T[i][j] = W1[j][i]
    for (int idx = tid; idx < 128 * 64; idx += 256) {
        int j = idx >> 6, i = idx & 63;
        sW[i * 129 + j] = W1[idx];
    }
    __syncthreads();

    // ff1 = relu(h @ W1^T + b1), stored transposed
    {
        const int j = tid & 127, t0 = (tid >> 7) * 16;
        float acc[16];
#pragma unroll
        for (int t = 0; t < 16; ++t) acc[t] = sb1[j];
        for (int i = 0; i < 64; ++i) {
            float w = sW[i * 129 + j];
            const float4* hp = reinterpret_cast<const float4*>(&sZT[i * 36 + t0]);
            float4 h0 = hp[0], h1 = hp[1], h2 = hp[2], h3 = hp[3];
            acc[0] = fmaf(w, h0.x, acc[0]);  acc[1] = fmaf(w, h0.y, acc[1]);
            acc[2] = fmaf(w, h0.z, acc[2]);  acc[3] = fmaf(w, h0.w, acc[3]);
            acc[4] = fmaf(w, h1.x, acc[4]);  acc[5] = fmaf(w, h1.y, acc[5]);
            acc[6] = fmaf(w, h1.z, acc[6]);  acc[7] = fmaf(w, h1.w, acc[7]);
            acc[8] = fmaf(w, h2.x, acc[8]);  acc[9] = fmaf(w, h2.y, acc[9]);
            acc[10] = fmaf(w, h2.z, acc[10]); acc[11] = fmaf(w, h2.w, acc[11]);
            acc[12] = fmaf(w, h3.x, acc[12]); acc[13] = fmaf(w, h3.y, acc[13]);
            acc[14] = fmaf(w, h3.z, acc[14]); acc[15] = fmaf(w, h3.w, acc[15]);
        }
#pragma unroll
        for (int t = 0; t < 16; ++t) sFT[j * 36 + t0 + t] = fmaxf(acc[t], 0.f);
    }
    __syncthreads();

    // W2T[p][i] = W2[i][p]
    for (int idx = tid; idx < 64 * 128; idx += 256) {
        int i = idx >> 7, p = idx & 127;
        sW[p * 65 + i] = W2[idx];
    }
    __syncthreads();

    // ff2 + residual + LayerNorm (wave = 8 tokens, lane = channel i)
    {
        const int i = tid & 63, t0 = (tid >> 6) * 8;
        float acc[8];
#pragma unroll
        for (int t = 0; t < 8; ++t) acc[t] = sb2[i];
        for (int p = 0; p < 128; ++p) {
            float w = sW[p * 65 + i];
            const float4* fp = reinterpret_cast<const float4*>(&sFT[p * 36 + t0]);
            float4 f0 = fp[0], f1 = fp[1];
            acc[0] = fmaf(w, f0.x, acc[0]); acc[1] = fmaf(w, f0.y, acc[1]);
            acc[2] = fmaf(w, f0.z, acc[2]); acc[3] = fmaf(w, f0.w, acc[3]);
            acc[4] = fmaf(w, f1.x, acc[4]); acc[5] = fmaf(w, f1.y, acc[5]);
            acc[6] = fmaf(w, f1.z, acc[6]); acc[7] = fmaf(w, f1.w, acc[7]);
        }
#pragma unroll
        for (int t = 0; t < 8; ++t) {
            float z = sZT[i * 36 + t0 + t] + acc[t];
            float s = z, ss = z * z;
            for (int off = 32; off; off >>= 1) {
                s += __shfl_xor(s, off);
                ss += __shfl_xor(ss, off);
            }
            float mu = s * 0.015625f;
            float var = ss * 0.015625f - mu * mu;
            float inv = rsqrtf(var + 1e-5f);
            sZT[i * 36 + t0 + t] = (z - mu) * inv * sg[i] + sbt[i];
        }
    }
    __syncthreads();

    // ---- k projection (+ l2norm) ----
    for (int idx = tid; idx < 64 * 64; idx += 256) {
        int j = idx >> 6, i = idx & 63;
        sW[i * 65 + j] = Wk[idx];
    }
    __syncthreads();
    {
        const int j = tid & 63, t0 = (tid >> 6) * 8;
        float acc[8] = {0, 0, 0, 0, 0, 0, 0, 0};
        for (int i = 0; i < 64; ++i) {
            float w = sW[i * 65 + j];
            const float4* hp = reinterpret_cast<const float4*>(&sZT[i * 36 + t0]);
            float4 h0 = hp[0], h1 = hp[1];
            acc[0] = fmaf(w, h0.x, acc[0]); acc[1] = fmaf(w, h0.y, acc[1]);
            acc[2] = fmaf(w, h0.z, acc[2]); acc[3] = fmaf(w, h0.w, acc[3]);
            acc[4] = fmaf(w, h1.x, acc[4]); acc[5] = fmaf(w, h1.y, acc[5]);
            acc[6] = fmaf(w, h1.z, acc[6]); acc[7] = fmaf(w, h1.w, acc[7]);
        }
#pragma unroll
        for (int t = 0; t < 8; ++t) {
            float ssq = acc[t] * acc[t];
            for (int off = 32; off; off >>= 1) ssq += __shfl_xor(ssq, off);
            float n = sqrtf(ssq);
            float scale = 1.f / fmaxf(n, 1e-12f);
            ks[(g0 + t0 + t) * 64 + j] = acc[t] * scale;
        }
    }
    __syncthreads();

    // ---- v projection ----
    for (int idx = tid; idx < 64 * 64; idx += 256) {
        int j = idx >> 6, i = idx & 63;
        sW[i * 65 + j] = Wv[idx];
    }
    __syncthreads();
    {
        const int j = tid & 63, t0 = (tid >> 6) * 8;
        float acc[8] = {0, 0, 0, 0, 0, 0, 0, 0};
        for (int i = 0; i < 64; ++i) {
            float w = sW[i * 65 + j];
            const float4* hp = reinterpret_cast<const float4*>(&sZT[i * 36 + t0]);
            float4 h0 = hp[0], h1 = hp[1];
            acc[0] = fmaf(w, h0.x, acc[0]); acc[1] = fmaf(w, h0.y, acc[1]);
            acc[2] = fmaf(w, h0.z, acc[2]); acc[3] = fmaf(w, h0.w, acc[3]);
            acc[4] = fmaf(w, h1.x, acc[4]); acc[5] = fmaf(w, h1.y, acc[5]);
            acc[6] = fmaf(w, h1.z, acc[6]); acc[7] = fmaf(w, h1.w, acc[7]);
        }
#pragma unroll
        for (int t = 0; t < 8; ++t) vs[(g0 + t0 + t) * 64 + j] = acc[t];
    }
    __syncthreads();

    // ---- q projection (first half only) ----
    if (l0 < 2048) {
        for (int idx = tid; idx < 64 * 64; idx += 256) {
            int j = idx >> 6, i = idx & 63;
            sW[i * 65 + j] = Wattn[idx];
        }
        __syncthreads();
        const int j = tid & 63, t0 = (tid >> 6) * 8;
        float acc[8] = {0, 0, 0, 0, 0, 0, 0, 0};
        for (int i = 0; i < 64; ++i) {
            float w = sW[i * 65 + j];
            const float4* hp = reinterpret_cast<const float4*>(&sZT[i * 36 + t0]);
            float4 h0 = hp[0], h1 = hp[1];
            acc[0] = fmaf(w, h0.x, acc[0]); acc[1] = fmaf(w, h0.y, acc[1]);
            acc[2] = fmaf(w, h0.z, acc[2]); acc[3] = fmaf(w, h0.w, acc[3]);
            acc[4] = fmaf(w, h1.x, acc[4]); acc[5] = fmaf(w, h1.y, acc[5]);
            acc[6] = fmaf(w, h1.z, acc[6]); acc[7] = fmaf(w, h1.w, acc[7]);
        }
#pragma unroll
        for (int t = 0; t < 8; ++t)
            qbuf[((size_t)b * 2048 + l0 + t0 + t) * 64 + j] = acc[t];
        __syncthreads();
    }

    // ---- q_last (only the last block of each batch) ----
    if (l0 == SEQL - TOK) {
        for (int idx = tid; idx < 64 * 64; idx += 256) {
            int j = idx >> 6, i = idx & 63;
            sW[i * 65 + j] = Wq[idx];
        }
        __syncthreads();
        const int j = tid & 63, wv = tid >> 6;
        if (wv == 3) {
            float a = 0.f;
            for (int i = 0; i < 64; ++i) a = fmaf(sW[i * 65 + j], sZT[i * 36 + 31], a);
            qlast[b * 64 + j] = a;
        }
    }
}

// ---------------------------------------------------------------------------
// Delta-rule scan: M <- M + (v - M k) k^T, T sequential steps.
// 1 block per batch. Thread owns rows r=tid>>2, cols (tid&3)*16..+15 of M in
// registers; dot reduced across the quad with 2 shuffles. No LDS, no barriers.
// ---------------------------------------------------------------------------
#define SCAN_STEP(K0, K1, K2, K3, V)                                            \
    do {                                                                        \
        float d0 = fmaf(m[0], K0.x, fmaf(m[1], K0.y, fmaf(m[2], K0.z, m[3] * K0.w))); \
        float d1 = fmaf(m[4], K1.x, fmaf(m[5], K1.y, fmaf(m[6], K1.z, m[7] * K1.w))); \
        float d2 = fmaf(m[8], K2.x, fmaf(m[9], K2.y, fmaf(m[10], K2.z, m[11] * K2.w))); \
        float d3 = fmaf(m[12], K3.x, fmaf(m[13], K3.y, fmaf(m[14], K3.z, m[15] * K3.w))); \
        float dd = (d0 + d1) + (d2 + d3);                                       \
        dd += __shfl_xor(dd, 1);                                                \
        dd += __shfl_xor(dd, 2);                                                \
        float uu = V - dd;                                                      \
        m[0] = fmaf(uu, K0.x, m[0]);  m[1] = fmaf(uu, K0.y, m[1]);              \
        m[2] = fmaf(uu, K0.z, m[2]);  m[3] = fmaf(uu, K0.w, m[3]);              \
        m[4] = fmaf(uu, K1.x, m[4]);  m[5] = fmaf(uu, K1.y, m[5]);              \
        m[6] = fmaf(uu, K1.z, m[6]);  m[7] = fmaf(uu, K1.w, m[7]);              \
        m[8] = fmaf(uu, K2.x, m[8]);  m[9] = fmaf(uu, K2.y, m[9]);              \
        m[10] = fmaf(uu, K2.z, m[10]); m[11] = fmaf(uu, K2.w, m[11]);           \
        m[12] = fmaf(uu, K3.x, m[12]); m[13] = fmaf(uu, K3.y, m[13]);           \
        m[14] = fmaf(uu, K3.z, m[14]); m[15] = fmaf(uu, K3.w, m[15]);           \
    } while (0)

__global__ __launch_bounds__(256) void scan_kernel(
    const float* __restrict__ ksb, const float* __restrict__ vsb,
    const float* __restrict__ Min, float* __restrict__ Mout, int T)
{
    const int b = blockIdx.x;
    const int tid = threadIdx.x;
    const int r = tid >> 2;
    const int c0 = (tid & 3) * 16;
    const float* kb = ksb + (size_t)b * T * 64 + c0;
    const float* vp = vsb + (size_t)b * T * 64 + r;

    float m[16];
    if (Min) {
        const float4* mi = reinterpret_cast<const float4*>(Min + ((size_t)b * 64 + r) * 64 + c0);
        float4 q0 = mi[0], q1 = mi[1], q2 = mi[2], q3 = mi[3];
        m[0] = q0.x; m[1] = q0.y; m[2] = q0.z; m[3] = q0.w;
        m[4] = q1.x; m[5] = q1.y; m[6] = q1.z; m[7] = q1.w;
        m[8] = q2.x; m[9] = q2.y; m[10] = q2.z; m[11] = q2.w;
        m[12] = q3.x; m[13] = q3.y; m[14] = q3.z; m[15] = q3.w;
    } else {
#pragma unroll
        for (int i = 0; i < 16; ++i) m[i] = 0.f;
    }

    float4 a0, a1, a2, a3, e0, e1, e2, e3;
    float va, ve;
    {
        const float4* kp = reinterpret_cast<const float4*>(kb);
        a0 = kp[0]; a1 = kp[1]; a2 = kp[2]; a3 = kp[3];
        va = vp[0];
    }
    for (int t = 0; t < T; t += 2) {
        {
            const float4* kp = reinterpret_cast<const float4*>(kb + (size_t)(t + 1) * 64);
            e0 = kp[0]; e1 = kp[1]; e2 = kp[2]; e3 = kp[3];
            ve = vp[(size_t)(t + 1) * 64];
        }
        SCAN_STEP(a0, a1, a2, a3, va);
        if (t + 2 < T) {
            const float4* kp = reinterpret_cast<const float4*>(kb + (size_t)(t + 2) * 64);
            a0 = kp[0]; a1 = kp[1]; a2 = kp[2]; a3 = kp[3];
            va = vp[(size_t)(t + 2) * 64];
        }
        SCAN_STEP(e0, e1, e2, e3, ve);
    }

    float4* mo = reinterpret_cast<float4*>(Mout + ((size_t)b * 64 + r) * 64 + c0);
    mo[0] = make_float4(m[0], m[1], m[2], m[3]);
    mo[1] = make_float4(m[4], m[5], m[6], m[7]);
    mo[2] = make_float4(m[8], m[9], m[10], m[11]);
    mo[3] = make_float4(m[12], m[13], m[14], m[15]);
}

// ---------------------------------------------------------------------------
// Attention read + second k/v projection, fused.
// ctx_t = M softmax(M^T q_t / 8); ks2 = l2norm(ctx Wk^T); vs2 = ctx Wv^T.
// Wave = 4 tokens at a time, lane = channel. Broadcast via __shfl.
// ---------------------------------------------------------------------------
__global__ __launch_bounds__(256) void attn_kernel(
    const float* __restrict__ q, const float* __restrict__ Mbuf,
    const float* __restrict__ Wk, const float* __restrict__ Wv,
    float* __restrict__ ks2, float* __restrict__ vs2)
{
    __shared__ float sM[64 * 65];
    __shared__ float sWkT[64 * 65];
    __shared__ float sWvT[64 * 65];
    const int b = blockIdx.y;
    const int grp = blockIdx.x;  // 16 groups x 128 tokens
    const int tid = threadIdx.x;
    const int lane = tid & 63, wv = tid >> 6;

    for (int idx = tid; idx < 4096; idx += 256) {
        int rr = idx >> 6, cc = idx & 63;
        sM[rr * 65 + cc] = Mbuf[(size_t)b * 4096 + idx];
        sWkT[cc * 65 + rr] = Wk[idx];
        sWvT[cc * 65 + rr] = Wv[idx];
    }
    __syncthreads();

    for (int g4 = wv; g4 < 32; g4 += 4) {
        const size_t base = (size_t)b * 2048 + grp * 128 + g4 * 4;
        float qv[4], s[4];
#pragma unroll
        for (int u = 0; u < 4; ++u) {
            qv[u] = q[(base + u) * 64 + lane];
            s[u] = 0.f;
        }
        for (int i = 0; i < 64; ++i) {
            float mi = sM[i * 65 + lane];
            s[0] = fmaf(mi, __shfl(qv[0], i), s[0]);
            s[1] = fmaf(mi, __shfl(qv[1], i), s[1]);
            s[2] = fmaf(mi, __shfl(qv[2], i), s[2]);
            s[3] = fmaf(mi, __shfl(qv[3], i), s[3]);
        }
        float p[4];
#pragma unroll
        for (int u = 0; u < 4; ++u) {
            float sv = s[u] * 0.125f;
            float mx = sv;
            for (int off = 32; off; off >>= 1) mx = fmaxf(mx, __shfl_xor(mx, off));
            float e = __expf(sv - mx);
            float sm = e;
            for (int off = 32; off; off >>= 1) sm += __shfl_xor(sm, off);
            p[u] = e / sm;
        }
        float cv[4] = {0.f, 0.f, 0.f, 0.f};
        for (int jj = 0; jj < 64; ++jj) {
            float mj = sM[lane * 65 + jj];
            cv[0] = fmaf(mj, __shfl(p[0], jj), cv[0]);
            cv[1] = fmaf(mj, __shfl(p[1], jj), cv[1]);
            cv[2] = fmaf(mj, __shfl(p[2], jj), cv[2]);
            cv[3] = fmaf(mj, __shfl(p[3], jj), cv[3]);
        }
        float k2[4] = {0.f, 0.f, 0.f, 0.f}, v2[4] = {0.f, 0.f, 0.f, 0.f};
        for (int h = 0; h < 64; ++h) {
            float wk = sWkT[h * 65 + lane], wvv = sWvT[h * 65 + lane];
            float c0 = __shfl(cv[0], h), c1 = __shfl(cv[1], h);
            float c2 = __shfl(cv[2], h), c3 = __shfl(cv[3], h);
            k2[0] = fmaf(wk, c0, k2[0]); v2[0] = fmaf(wvv, c0, v2[0]);
            k2[1] = fmaf(wk, c1, k2[1]); v2[1] = fmaf(wvv, c1, v2[1]);
            k2[2] = fmaf(wk, c2, k2[2]); v2[2] = fmaf(wvv, c2, v2[2]);
            k2[3] = fmaf(wk, c3, k2[3]); v2[3] = fmaf(wvv, c3, v2[3]);
        }
#pragma unroll
        for (int u = 0; u < 4; ++u) {
            float ssq = k2[u] * k2[u];
            for (int off = 32; off; off >>= 1) ssq += __shfl_xor(ssq, off);
            float n = sqrtf(ssq);
            float sc2 = 1.f / fmaxf(n, 1e-12f);
            ks2[(base + u) * 64 + lane] = k2[u] * sc2;
            vs2[(base + u) * 64 + lane] = v2[u];
        }
    }
}

// ---------------------------------------------------------------------------
// Output: read = M2 @ q_last; out = read @ Wout^T + bout
// ---------------------------------------------------------------------------
__global__ __launch_bounds__(128) void out_kernel(
    const float* __restrict__ M2, const float* __restrict__ qlast,
    const float* __restrict__ Wout, const float* __restrict__ bout,
    float* __restrict__ out)
{
    const int b = blockIdx.x;
    const int tid = threadIdx.x;
    __shared__ float sq[64], sread[64];
    if (tid < 64) sq[tid] = qlast[b * 64 + tid];
    __syncthreads();
    if (tid < 64) {
        const float* Mr = M2 + ((size_t)b * 64 + tid) * 64;
        float acc = 0.f;
        for (int j = 0; j < 64; ++j) acc = fmaf(Mr[j], sq[j], acc);
        sread[tid] = acc;
    }
    __syncthreads();
    float acc = bout[tid];
    for (int h = 0; h < 64; ++h) acc = fmaf(Wout[tid * 64 + h], sread[h], acc);
    out[b * 128 + tid] = acc;
}

// ---------------------------------------------------------------------------
extern "C" void kernel_launch(void* const* d_in, const int* in_sizes, int n_in,
                              void* d_out, int out_size, void* d_ws, size_t ws_size,
                              hipStream_t stream)
{
    const int* x        = (const int*)d_in[0];
    const float* embed  = (const float*)d_in[1];
    const float* W1     = (const float*)d_in[2];
    const float* b1     = (const float*)d_in[3];
    const float* W2     = (const float*)d_in[4];
    const float* b2     = (const float*)d_in[5];
    const float* ln_g   = (const float*)d_in[6];
    const float* ln_b   = (const float*)d_in[7];
    const float* Wk     = (const float*)d_in[8];
    const float* Wv     = (const float*)d_in[9];
    const float* Wq     = (const float*)d_in[10];
    const float* Wattn  = (const float*)d_in[11];
    const float* Wout   = (const float*)d_in[12];
    const float* bout   = (const float*)d_in[13];

    // workspace layout (floats): ks | vs | q | qlast | M | M2  (~162 MB)
    float* ws = (float*)d_ws;
    float* ks = ws;
    float* vs = ks + (size_t)NB * SEQL * 64;
    float* qb = vs + (size_t)NB * SEQL * 64;
    float* ql = qb + (size_t)NB * 2048 * 64;
    float* M  = ql + (size_t)NB * 64;
    float* M2 = M + (size_t)NB * 64 * 64;
    if (ws_size < (size_t)(M2 + (size_t)NB * 64 * 64 - ws) * sizeof(float)) return;

    hipLaunchKernelGGL(encoder_kernel, dim3((NB * SEQL) / TOK), dim3(256), 0, stream,
                       x, embed, W1, b1, W2, b2, ln_g, ln_b, Wk, Wv, Wq, Wattn,
                       ks, vs, qb, ql);
    hipLaunchKernelGGL(scan_kernel, dim3(NB), dim3(256), 0, stream,
                       ks, vs, (const float*)nullptr, M, SEQL);
    // ks2/vs2 reuse the ks/vs buffers (scan1 has fully consumed them)
    hipLaunchKernelGGL(attn_kernel, dim3(16, NB), dim3(256), 0, stream,
                       qb, M, Wk, Wv, ks, vs);
    hipLaunchKernelGGL(scan_kernel, dim3(NB), dim3(256), 0, stream,
                       ks, vs, M, M2, 2048);
    hipLaunchKernelGGL(out_kernel, dim3(NB), dim3(128), 0, stream,
                       M2, ql, Wout, bout, (float*)d_out);
}

// Round 2
// 1402.638 us; speedup vs baseline: 1.9392x; 1.9392x over previous
//
#include <hip/hip_runtime.h>

#define H64 64
#define SEQL 4096
#define NB 64
#define TOK 32

// ---------------------------------------------------------------------------
// Encoder: embed -> FF(relu) -> residual -> LayerNorm -> k (l2norm), v, q, qlast
// One block = 32 tokens (never straddles a batch: 4096 % 32 == 0).
// ---------------------------------------------------------------------------
__global__ __launch_bounds__(256) void encoder_kernel(
    const int* __restrict__ x, const float* __restrict__ embed,
    const float* __restrict__ W1, const float* __restrict__ b1,
    const float* __restrict__ W2, const float* __restrict__ b2,
    const float* __restrict__ ln_g, const float* __restrict__ ln_b,
    const float* __restrict__ Wk, const float* __restrict__ Wv,
    const float* __restrict__ Wq, const float* __restrict__ Wattn,
    float* __restrict__ ks, float* __restrict__ vs,
    float* __restrict__ qbuf, float* __restrict__ qlast)
{
    __shared__ __align__(16) float sW[128 * 65];   // W1T[64][129] / W2T[128][65] / WT[64][65]
    __shared__ __align__(16) float sZT[64 * 36];   // h / hidden, transposed [i][t]
    __shared__ __align__(16) float sFT[128 * 36];  // ff1, transposed [p][t]
    __shared__ float sb1[128], sb2[64], sg[64], sbt[64];

    const int tid = threadIdx.x;
    const size_t g0 = (size_t)blockIdx.x * TOK;
    const int b = (int)(g0 >> 12);
    const int l0 = (int)(g0 & (SEQL - 1));

    if (tid < 128) sb1[tid] = b1[tid];
    else if (tid < 192) sb2[tid - 128] = b2[tid - 128];
    else { sg[tid - 192] = ln_g[tid - 192]; sbt[tid - 192] = ln_b[tid - 192]; }

    // h
    for (int idx = tid; idx < TOK * 64; idx += 256) {
        int t = idx >> 6, i = idx & 63;
        sZT[i * 36 + t] = embed[(size_t)x[g0 + t] * 64 + i];
    }
    // W1T[i][j] = W1[j][i]
    for (int idx = tid; idx < 128 * 64; idx += 256) {
        int j = idx >> 6, i = idx & 63;
        sW[i * 129 + j] = W1[idx];
    }
    __syncthreads();

    // ff1 = relu(h @ W1^T + b1), stored transposed
    {
        const int j = tid & 127, t0 = (tid >> 7) * 16;
        float acc[16];
#pragma unroll
        for (int t = 0; t < 16; ++t) acc[t] = sb1[j];
        for (int i = 0; i < 64; ++i) {
            float w = sW[i * 129 + j];
            const float4* hp = reinterpret_cast<const float4*>(&sZT[i * 36 + t0]);
            float4 h0 = hp[0], h1 = hp[1], h2 = hp[2], h3 = hp[3];
            acc[0] = fmaf(w, h0.x, acc[0]);  acc[1] = fmaf(w, h0.y, acc[1]);
            acc[2] = fmaf(w, h0.z, acc[2]);  acc[3] = fmaf(w, h0.w, acc[3]);
            acc[4] = fmaf(w, h1.x, acc[4]);  acc[5] = fmaf(w, h1.y, acc[5]);
            acc[6] = fmaf(w, h1.z, acc[6]);  acc[7] = fmaf(w, h1.w, acc[7]);
            acc[8] = fmaf(w, h2.x, acc[8]);  acc[9] = fmaf(w, h2.y, acc[9]);
            acc[10] = fmaf(w, h2.z, acc[10]); acc[11] = fmaf(w, h2.w, acc[11]);
            acc[12] = fmaf(w, h3.x, acc[12]); acc[13] = fmaf(w, h3.y, acc[13]);
            acc[14] = fmaf(w, h3.z, acc[14]); acc[15] = fmaf(w, h3.w, acc[15]);
        }
#pragma unroll
        for (int t = 0; t < 16; ++t) sFT[j * 36 + t0 + t] = fmaxf(acc[t], 0.f);
    }
    __syncthreads();

    // W2T[p][i] = W2[i][p]
    for (int idx = tid; idx < 64 * 128; idx += 256) {
        int i = idx >> 7, p = idx & 127;
        sW[p * 65 + i] = W2[idx];
    }
    __syncthreads();

    // ff2 + residual + LayerNorm (wave = 8 tokens, lane = channel i)
    {
        const int i = tid & 63, t0 = (tid >> 6) * 8;
        float acc[8];
#pragma unroll
        for (int t = 0; t < 8; ++t) acc[t] = sb2[i];
        for (int p = 0; p < 128; ++p) {
            float w = sW[p * 65 + i];
            const float4* fp = reinterpret_cast<const float4*>(&sFT[p * 36 + t0]);
            float4 f0 = fp[0], f1 = fp[1];
            acc[0] = fmaf(w, f0.x, acc[0]); acc[1] = fmaf(w, f0.y, acc[1]);
            acc[2] = fmaf(w, f0.z, acc[2]); acc[3] = fmaf(w, f0.w, acc[3]);
            acc[4] = fmaf(w, f1.x, acc[4]); acc[5] = fmaf(w, f1.y, acc[5]);
            acc[6] = fmaf(w, f1.z, acc[6]); acc[7] = fmaf(w, f1.w, acc[7]);
        }
#pragma unroll
        for (int t = 0; t < 8; ++t) {
            float z = sZT[i * 36 + t0 + t] + acc[t];
            float s = z, ss = z * z;
            for (int off = 32; off; off >>= 1) {
                s += __shfl_xor(s, off);
                ss += __shfl_xor(ss, off);
            }
            float mu = s * 0.015625f;
            float var = ss * 0.015625f - mu * mu;
            float inv = rsqrtf(var + 1e-5f);
            sZT[i * 36 + t0 + t] = (z - mu) * inv * sg[i] + sbt[i];
        }
    }
    __syncthreads();

    // ---- k projection (+ l2norm) ----
    for (int idx = tid; idx < 64 * 64; idx += 256) {
        int j = idx >> 6, i = idx & 63;
        sW[i * 65 + j] = Wk[idx];
    }
    __syncthreads();
    {
        const int j = tid & 63, t0 = (tid >> 6) * 8;
        float acc[8] = {0, 0, 0, 0, 0, 0, 0, 0};
        for (int i = 0; i < 64; ++i) {
            float w = sW[i * 65 + j];
            const float4* hp = reinterpret_cast<const float4*>(&sZT[i * 36 + t0]);
            float4 h0 = hp[0], h1 = hp[1];
            acc[0] = fmaf(w, h0.x, acc[0]); acc[1] = fmaf(w, h0.y, acc[1]);
            acc[2] = fmaf(w, h0.z, acc[2]); acc[3] = fmaf(w, h0.w, acc[3]);
            acc[4] = fmaf(w, h1.x, acc[4]); acc[5] = fmaf(w, h1.y, acc[5]);
            acc[6] = fmaf(w, h1.z, acc[6]); acc[7] = fmaf(w, h1.w, acc[7]);
        }
#pragma unroll
        for (int t = 0; t < 8; ++t) {
            float ssq = acc[t] * acc[t];
            for (int off = 32; off; off >>= 1) ssq += __shfl_xor(ssq, off);
            float n = sqrtf(ssq);
            float scale = 1.f / fmaxf(n, 1e-12f);
            ks[(g0 + t0 + t) * 64 + j] = acc[t] * scale;
        }
    }
    __syncthreads();

    // ---- v projection ----
    for (int idx = tid; idx < 64 * 64; idx += 256) {
        int j = idx >> 6, i = idx & 63;
        sW[i * 65 + j] = Wv[idx];
    }
    __syncthreads();
    {
        const int j = tid & 63, t0 = (tid >> 6) * 8;
        float acc[8] = {0, 0, 0, 0, 0, 0, 0, 0};
        for (int i = 0; i < 64; ++i) {
            float w = sW[i * 65 + j];
            const float4* hp = reinterpret_cast<const float4*>(&sZT[i * 36 + t0]);
            float4 h0 = hp[0], h1 = hp[1];
            acc[0] = fmaf(w, h0.x, acc[0]); acc[1] = fmaf(w, h0.y, acc[1]);
            acc[2] = fmaf(w, h0.z, acc[2]); acc[3] = fmaf(w, h0.w, acc[3]);
            acc[4] = fmaf(w, h1.x, acc[4]); acc[5] = fmaf(w, h1.y, acc[5]);
            acc[6] = fmaf(w, h1.z, acc[6]); acc[7] = fmaf(w, h1.w, acc[7]);
        }
#pragma unroll
        for (int t = 0; t < 8; ++t) vs[(g0 + t0 + t) * 64 + j] = acc[t];
    }
    __syncthreads();

    // ---- q projection (first half only) ----
    if (l0 < 2048) {
        for (int idx = tid; idx < 64 * 64; idx += 256) {
            int j = idx >> 6, i = idx & 63;
            sW[i * 65 + j] = Wattn[idx];
        }
        __syncthreads();
        const int j = tid & 63, t0 = (tid >> 6) * 8;
        float acc[8] = {0, 0, 0, 0, 0, 0, 0, 0};
        for (int i = 0; i < 64; ++i) {
            float w = sW[i * 65 + j];
            const float4* hp = reinterpret_cast<const float4*>(&sZT[i * 36 + t0]);
            float4 h0 = hp[0], h1 = hp[1];
            acc[0] = fmaf(w, h0.x, acc[0]); acc[1] = fmaf(w, h0.y, acc[1]);
            acc[2] = fmaf(w, h0.z, acc[2]); acc[3] = fmaf(w, h0.w, acc[3]);
            acc[4] = fmaf(w, h1.x, acc[4]); acc[5] = fmaf(w, h1.y, acc[5]);
            acc[6] = fmaf(w, h1.z, acc[6]); acc[7] = fmaf(w, h1.w, acc[7]);
        }
#pragma unroll
        for (int t = 0; t < 8; ++t)
            qbuf[((size_t)b * 2048 + l0 + t0 + t) * 64 + j] = acc[t];
        __syncthreads();
    }

    // ---- q_last (only the last block of each batch) ----
    if (l0 == SEQL - TOK) {
        for (int idx = tid; idx < 64 * 64; idx += 256) {
            int j = idx >> 6, i = idx & 63;
            sW[i * 65 + j] = Wq[idx];
        }
        __syncthreads();
        const int j = tid & 63, wv = tid >> 6;
        if (wv == 3) {
            float a = 0.f;
            for (int i = 0; i < 64; ++i) a = fmaf(sW[i * 65 + j], sZT[i * 36 + 31], a);
            qlast[b * 64 + j] = a;
        }
    }
}

// ---------------------------------------------------------------------------
// Chunked delta scan, phase A: per chunk of C tokens compute
//   P = prod_t (I - k_t k_t^T),  Q = sum_t v_t k_t^T prod_{s>t}(I - k_s k_s^T)
// via the same rank-1 recurrence as the reference (P: u=-Pk; Q: u=v-Qk),
// starting from (I, 0). Fully parallel across chunks. P,Q (64x64 each) are
// written IN PLACE over the first 64 rows of the consumed k / v chunk
// (all reads of the region finish before the end-of-kernel writes).
// Thread r=tid>>2 owns row r, cols (tid&3)*16..+15 of P and Q in registers.
// ---------------------------------------------------------------------------
#define STEP2(K0, K1, K2, K3, V)                                                \
    do {                                                                        \
        float dp0 = fmaf(p[0], K0.x, fmaf(p[1], K0.y, fmaf(p[2], K0.z, p[3] * K0.w))); \
        float dp1 = fmaf(p[4], K1.x, fmaf(p[5], K1.y, fmaf(p[6], K1.z, p[7] * K1.w))); \
        float dp2 = fmaf(p[8], K2.x, fmaf(p[9], K2.y, fmaf(p[10], K2.z, p[11] * K2.w))); \
        float dp3 = fmaf(p[12], K3.x, fmaf(p[13], K3.y, fmaf(p[14], K3.z, p[15] * K3.w))); \
        float dq0 = fmaf(q[0], K0.x, fmaf(q[1], K0.y, fmaf(q[2], K0.z, q[3] * K0.w))); \
        float dq1 = fmaf(q[4], K1.x, fmaf(q[5], K1.y, fmaf(q[6], K1.z, q[7] * K1.w))); \
        float dq2 = fmaf(q[8], K2.x, fmaf(q[9], K2.y, fmaf(q[10], K2.z, q[11] * K2.w))); \
        float dq3 = fmaf(q[12], K3.x, fmaf(q[13], K3.y, fmaf(q[14], K3.z, q[15] * K3.w))); \
        float ddp = (dp0 + dp1) + (dp2 + dp3);                                  \
        float ddq = (dq0 + dq1) + (dq2 + dq3);                                  \
        ddp += __shfl_xor(ddp, 1);  ddq += __shfl_xor(ddq, 1);                  \
        ddp += __shfl_xor(ddp, 2);  ddq += __shfl_xor(ddq, 2);                  \
        float up = -ddp;                                                        \
        float uq = V - ddq;                                                     \
        p[0] = fmaf(up, K0.x, p[0]);   q[0] = fmaf(uq, K0.x, q[0]);             \
        p[1] = fmaf(up, K0.y, p[1]);   q[1] = fmaf(uq, K0.y, q[1]);             \
        p[2] = fmaf(up, K0.z, p[2]);   q[2] = fmaf(uq, K0.z, q[2]);             \
        p[3] = fmaf(up, K0.w, p[3]);   q[3] = fmaf(uq, K0.w, q[3]);             \
        p[4] = fmaf(up, K1.x, p[4]);   q[4] = fmaf(uq, K1.x, q[4]);             \
        p[5] = fmaf(up, K1.y, p[5]);   q[5] = fmaf(uq, K1.y, q[5]);             \
        p[6] = fmaf(up, K1.z, p[6]);   q[6] = fmaf(uq, K1.z, q[6]);             \
        p[7] = fmaf(up, K1.w, p[7]);   q[7] = fmaf(uq, K1.w, q[7]);             \
        p[8] = fmaf(up, K2.x, p[8]);   q[8] = fmaf(uq, K2.x, q[8]);             \
        p[9] = fmaf(up, K2.y, p[9]);   q[9] = fmaf(uq, K2.y, q[9]);             \
        p[10] = fmaf(up, K2.z, p[10]); q[10] = fmaf(uq, K2.z, q[10]);           \
        p[11] = fmaf(up, K2.w, p[11]); q[11] = fmaf(uq, K2.w, q[11]);           \
        p[12] = fmaf(up, K3.x, p[12]); q[12] = fmaf(uq, K3.x, q[12]);           \
        p[13] = fmaf(up, K3.y, p[13]); q[13] = fmaf(uq, K3.y, q[13]);           \
        p[14] = fmaf(up, K3.z, p[14]); q[14] = fmaf(uq, K3.z, q[14]);           \
        p[15] = fmaf(up, K3.w, p[15]); q[15] = fmaf(uq, K3.w, q[15]);           \
    } while (0)

__global__ __launch_bounds__(256) void chunk_kernel(
    float* __restrict__ ksb, float* __restrict__ vsb, int C)
{
    const int job = blockIdx.x;
    const int tid = threadIdx.x;
    const int r = tid >> 2;
    const int c0 = (tid & 3) * 16;
    float* kc = ksb + (size_t)job * C * 64;
    float* vc = vsb + (size_t)job * C * 64;

    float p[16], q[16];
#pragma unroll
    for (int j = 0; j < 16; ++j) { p[j] = (c0 + j == r) ? 1.f : 0.f; q[j] = 0.f; }

    const float* kb = kc + c0;
    const float* vp = vc + r;

    float4 a0, a1, a2, a3, e0, e1, e2, e3;
    float va, ve;
    {
        const float4* kp = reinterpret_cast<const float4*>(kb);
        a0 = kp[0]; a1 = kp[1]; a2 = kp[2]; a3 = kp[3];
        va = vp[0];
    }
    for (int t = 0; t < C; t += 2) {
        {
            const float4* kp = reinterpret_cast<const float4*>(kb + (size_t)(t + 1) * 64);
            e0 = kp[0]; e1 = kp[1]; e2 = kp[2]; e3 = kp[3];
            ve = vp[(size_t)(t + 1) * 64];
        }
        STEP2(a0, a1, a2, a3, va);
        if (t + 2 < C) {
            const float4* kp = reinterpret_cast<const float4*>(kb + (size_t)(t + 2) * 64);
            a0 = kp[0]; a1 = kp[1]; a2 = kp[2]; a3 = kp[3];
            va = vp[(size_t)(t + 2) * 64];
        }
        STEP2(e0, e1, e2, e3, ve);
    }

    // write P over k-chunk, Q over v-chunk (this block is the only reader)
    float4* po = reinterpret_cast<float4*>(kc + r * 64 + c0);
    po[0] = make_float4(p[0], p[1], p[2], p[3]);
    po[1] = make_float4(p[4], p[5], p[6], p[7]);
    po[2] = make_float4(p[8], p[9], p[10], p[11]);
    po[3] = make_float4(p[12], p[13], p[14], p[15]);
    float4* qo = reinterpret_cast<float4*>(vc + r * 64 + c0);
    qo[0] = make_float4(q[0], q[1], q[2], q[3]);
    qo[1] = make_float4(q[4], q[5], q[6], q[7]);
    qo[2] = make_float4(q[8], q[9], q[10], q[11]);
    qo[3] = make_float4(q[12], q[13], q[14], q[15]);
}

// ---------------------------------------------------------------------------
// Chunked delta scan, phase B: per batch, M <- M*P_c + Q_c over nc chunks.
// One block per batch, M double-buffered in LDS (stride 68 to keep the
// column broadcast reads conflict-free), P double-buffered in LDS with
// register prefetch of the next chunk during the current matmul.
// ---------------------------------------------------------------------------
__global__ __launch_bounds__(256) void combine_kernel(
    const float* __restrict__ Pb, const float* __restrict__ Qb,
    const float* __restrict__ Min, float* __restrict__ Mout,
    int nc, int chunk_stride)
{
    __shared__ __align__(16) float sM[2][64 * 68];
    __shared__ __align__(16) float sP[2][64 * 64];
    const int b = blockIdx.x;
    const int tid = threadIdx.x;
    const int r = tid >> 2;
    const int j0 = (tid & 3) * 16;

    // init M
    if (Min) {
        const float4* mi = reinterpret_cast<const float4*>(Min + ((size_t)b * 64 + r) * 64 + j0);
        float4* mo = reinterpret_cast<float4*>(&sM[0][r * 68 + j0]);
#pragma unroll
        for (int u = 0; u < 4; ++u) mo[u] = mi[u];
    } else {
#pragma unroll
        for (int u = 0; u < 16; ++u) sM[0][r * 68 + j0 + u] = 0.f;
    }
    // stage P_0
    {
        const float4* g = reinterpret_cast<const float4*>(Pb + (size_t)b * nc * chunk_stride);
        float4* s = reinterpret_cast<float4*>(sP[0]);
        for (int i = tid; i < 1024; i += 256) s[i] = g[i];
    }
    __syncthreads();

    int cur = 0;
    for (int c = 0; c < nc; ++c) {
        const size_t cbase = (size_t)(b * nc + c) * chunk_stride;
        float4 rp0, rp1, rp2, rp3;
        if (c + 1 < nc) {
            const float4* g = reinterpret_cast<const float4*>(Pb + cbase + chunk_stride);
            rp0 = g[tid]; rp1 = g[tid + 256]; rp2 = g[tid + 512]; rp3 = g[tid + 768];
        }
        float4 rq0, rq1, rq2, rq3;
        {
            const float4* gq = reinterpret_cast<const float4*>(Qb + cbase + r * 64 + j0);
            rq0 = gq[0]; rq1 = gq[1]; rq2 = gq[2]; rq3 = gq[3];
        }
        float acc[16];
#pragma unroll
        for (int u = 0; u < 16; ++u) acc[u] = 0.f;
        const float* Mrow = &sM[cur][r * 68];
        const float* Pl = sP[c & 1];
#pragma unroll
        for (int mg = 0; mg < 16; ++mg) {
            float4 a = *reinterpret_cast<const float4*>(Mrow + mg * 4);
#pragma unroll
            for (int e2 = 0; e2 < 4; ++e2) {
                float am = (e2 == 0) ? a.x : (e2 == 1) ? a.y : (e2 == 2) ? a.z : a.w;
                const float4* pr = reinterpret_cast<const float4*>(Pl + (mg * 4 + e2) * 64 + j0);
                float4 p0 = pr[0], p1 = pr[1], p2 = pr[2], p3 = pr[3];
                acc[0] = fmaf(am, p0.x, acc[0]);  acc[1] = fmaf(am, p0.y, acc[1]);
                acc[2] = fmaf(am, p0.z, acc[2]);  acc[3] = fmaf(am, p0.w, acc[3]);
                acc[4] = fmaf(am, p1.x, acc[4]);  acc[5] = fmaf(am, p1.y, acc[5]);
                acc[6] = fmaf(am, p1.z, acc[6]);  acc[7] = fmaf(am, p1.w, acc[7]);
                acc[8] = fmaf(am, p2.x, acc[8]);  acc[9] = fmaf(am, p2.y, acc[9]);
                acc[10] = fmaf(am, p2.z, acc[10]); acc[11] = fmaf(am, p2.w, acc[11]);
                acc[12] = fmaf(am, p3.x, acc[12]); acc[13] = fmaf(am, p3.y, acc[13]);
                acc[14] = fmaf(am, p3.z, acc[14]); acc[15] = fmaf(am, p3.w, acc[15]);
            }
        }
        const int nxt = cur ^ 1;
        float* om = &sM[nxt][r * 68 + j0];
        om[0] = acc[0] + rq0.x;  om[1] = acc[1] + rq0.y;
        om[2] = acc[2] + rq0.z;  om[3] = acc[3] + rq0.w;
        om[4] = acc[4] + rq1.x;  om[5] = acc[5] + rq1.y;
        om[6] = acc[6] + rq1.z;  om[7] = acc[7] + rq1.w;
        om[8] = acc[8] + rq2.x;  om[9] = acc[9] + rq2.y;
        om[10] = acc[10] + rq2.z; om[11] = acc[11] + rq2.w;
        om[12] = acc[12] + rq3.x; om[13] = acc[13] + rq3.y;
        om[14] = acc[14] + rq3.z; om[15] = acc[15] + rq3.w;
        if (c + 1 < nc) {
            float4* s = reinterpret_cast<float4*>(sP[(c + 1) & 1]);
            s[tid] = rp0; s[tid + 256] = rp1; s[tid + 512] = rp2; s[tid + 768] = rp3;
        }
        __syncthreads();
        cur = nxt;
    }

    float4* mo = reinterpret_cast<float4*>(Mout + ((size_t)b * 64 + r) * 64 + j0);
    const float* fm = &sM[cur][r * 68 + j0];
    mo[0] = make_float4(fm[0], fm[1], fm[2], fm[3]);
    mo[1] = make_float4(fm[4], fm[5], fm[6], fm[7]);
    mo[2] = make_float4(fm[8], fm[9], fm[10], fm[11]);
    mo[3] = make_float4(fm[12], fm[13], fm[14], fm[15]);
}

// ---------------------------------------------------------------------------
// Attention read + second k/v projection, fused.
// ---------------------------------------------------------------------------
__global__ __launch_bounds__(256) void attn_kernel(
    const float* __restrict__ q, const float* __restrict__ Mbuf,
    const float* __restrict__ Wk, const float* __restrict__ Wv,
    float* __restrict__ ks2, float* __restrict__ vs2)
{
    __shared__ float sM[64 * 65];
    __shared__ float sWkT[64 * 65];
    __shared__ float sWvT[64 * 65];
    const int b = blockIdx.y;
    const int grp = blockIdx.x;  // 16 groups x 128 tokens
    const int tid = threadIdx.x;
    const int lane = tid & 63, wv = tid >> 6;

    for (int idx = tid; idx < 4096; idx += 256) {
        int rr = idx >> 6, cc = idx & 63;
        sM[rr * 65 + cc] = Mbuf[(size_t)b * 4096 + idx];
        sWkT[cc * 65 + rr] = Wk[idx];
        sWvT[cc * 65 + rr] = Wv[idx];
    }
    __syncthreads();

    for (int g4 = wv; g4 < 32; g4 += 4) {
        const size_t base = (size_t)b * 2048 + grp * 128 + g4 * 4;
        float qv[4], s[4];
#pragma unroll
        for (int u = 0; u < 4; ++u) {
            qv[u] = q[(base + u) * 64 + lane];
            s[u] = 0.f;
        }
        for (int i = 0; i < 64; ++i) {
            float mi = sM[i * 65 + lane];
            s[0] = fmaf(mi, __shfl(qv[0], i), s[0]);
            s[1] = fmaf(mi, __shfl(qv[1], i), s[1]);
            s[2] = fmaf(mi, __shfl(qv[2], i), s[2]);
            s[3] = fmaf(mi, __shfl(qv[3], i), s[3]);
        }
        float p[4];
#pragma unroll
        for (int u = 0; u < 4; ++u) {
            float sv = s[u] * 0.125f;
            float mx = sv;
            for (int off = 32; off; off >>= 1) mx = fmaxf(mx, __shfl_xor(mx, off));
            float e = __expf(sv - mx);
            float sm = e;
            for (int off = 32; off; off >>= 1) sm += __shfl_xor(sm, off);
            p[u] = e / sm;
        }
        float cv[4] = {0.f, 0.f, 0.f, 0.f};
        for (int jj = 0; jj < 64; ++jj) {
            float mj = sM[lane * 65 + jj];
            cv[0] = fmaf(mj, __shfl(p[0], jj), cv[0]);
            cv[1] = fmaf(mj, __shfl(p[1], jj), cv[1]);
            cv[2] = fmaf(mj, __shfl(p[2], jj), cv[2]);
            cv[3] = fmaf(mj, __shfl(p[3], jj), cv[3]);
        }
        float k2[4] = {0.f, 0.f, 0.f, 0.f}, v2[4] = {0.f, 0.f, 0.f, 0.f};
        for (int h = 0; h < 64; ++h) {
            float wk = sWkT[h * 65 + lane], wvv = sWvT[h * 65 + lane];
            float c0 = __shfl(cv[0], h), c1 = __shfl(cv[1], h);
            float c2 = __shfl(cv[2], h), c3 = __shfl(cv[3], h);
            k2[0] = fmaf(wk, c0, k2[0]); v2[0] = fmaf(wvv, c0, v2[0]);
            k2[1] = fmaf(wk, c1, k2[1]); v2[1] = fmaf(wvv, c1, v2[1]);
            k2[2] = fmaf(wk, c2, k2[2]); v2[2] = fmaf(wvv, c2, v2[2]);
            k2[3] = fmaf(wk, c3, k2[3]); v2[3] = fmaf(wvv, c3, v2[3]);
        }
#pragma unroll
        for (int u = 0; u < 4; ++u) {
            float ssq = k2[u] * k2[u];
            for (int off = 32; off; off >>= 1) ssq += __shfl_xor(ssq, off);
            float n = sqrtf(ssq);
            float sc2 = 1.f / fmaxf(n, 1e-12f);
            ks2[(base + u) * 64 + lane] = k2[u] * sc2;
            vs2[(base + u) * 64 + lane] = v2[u];
        }
    }
}

// ---------------------------------------------------------------------------
// Output: read = M2 @ q_last; out = read @ Wout^T + bout
// ---------------------------------------------------------------------------
__global__ __launch_bounds__(128) void out_kernel(
    const float* __restrict__ M2, const float* __restrict__ qlast,
    const float* __restrict__ Wout, const float* __restrict__ bout,
    float* __restrict__ out)
{
    const int b = blockIdx.x;
    const int tid = threadIdx.x;
    __shared__ float sq[64], sread[64];
    if (tid < 64) sq[tid] = qlast[b * 64 + tid];
    __syncthreads();
    if (tid < 64) {
        const float* Mr = M2 + ((size_t)b * 64 + tid) * 64;
        float acc = 0.f;
        for (int j = 0; j < 64; ++j) acc = fmaf(Mr[j], sq[j], acc);
        sread[tid] = acc;
    }
    __syncthreads();
    float acc = bout[tid];
    for (int h = 0; h < 64; ++h) acc = fmaf(Wout[tid * 64 + h], sread[h], acc);
    out[b * 128 + tid] = acc;
}

// ---------------------------------------------------------------------------
extern "C" void kernel_launch(void* const* d_in, const int* in_sizes, int n_in,
                              void* d_out, int out_size, void* d_ws, size_t ws_size,
                              hipStream_t stream)
{
    const int* x        = (const int*)d_in[0];
    const float* embed  = (const float*)d_in[1];
    const float* W1     = (const float*)d_in[2];
    const float* b1     = (const float*)d_in[3];
    const float* W2     = (const float*)d_in[4];
    const float* b2     = (const float*)d_in[5];
    const float* ln_g   = (const float*)d_in[6];
    const float* ln_b   = (const float*)d_in[7];
    const float* Wk     = (const float*)d_in[8];
    const float* Wv     = (const float*)d_in[9];
    const float* Wq     = (const float*)d_in[10];
    const float* Wattn  = (const float*)d_in[11];
    const float* Wout   = (const float*)d_in[12];
    const float* bout   = (const float*)d_in[13];

    // workspace layout (floats): ks | vs | q | qlast | M | M2 (same as round 1)
    float* ws = (float*)d_ws;
    float* ks = ws;
    float* vs = ks + (size_t)NB * SEQL * 64;
    float* qb = vs + (size_t)NB * SEQL * 64;
    float* ql = qb + (size_t)NB * 2048 * 64;
    float* M  = ql + (size_t)NB * 64;
    float* M2 = M + (size_t)NB * 64 * 64;
    if (ws_size < (size_t)(M2 + (size_t)NB * 64 * 64 - ws) * sizeof(float)) return;

    hipLaunchKernelGGL(encoder_kernel, dim3((NB * SEQL) / TOK), dim3(256), 0, stream,
                       x, embed, W1, b1, W2, b2, ln_g, ln_b, Wk, Wv, Wq, Wattn,
                       ks, vs, qb, ql);

    // scan 1: L=4096, C=256 -> 16 chunks/batch, 1024 parallel chunk jobs
    const int C1 = 256, nc1 = SEQL / C1;
    hipLaunchKernelGGL(chunk_kernel, dim3(NB * nc1), dim3(256), 0, stream, ks, vs, C1);
    hipLaunchKernelGGL(combine_kernel, dim3(NB), dim3(256), 0, stream,
                       ks, vs, (const float*)nullptr, M, nc1, C1 * 64);

    // attention + second k/v projection (ks2/vs2 reuse ks/vs: scan1 consumed them)
    hipLaunchKernelGGL(attn_kernel, dim3(16, NB), dim3(256), 0, stream,
                       qb, M, Wk, Wv, ks, vs);

    // scan 2: L=2048, C=128 -> 16 chunks/batch, 1024 parallel chunk jobs
    const int C2 = 128, nc2 = 2048 / C2;
    hipLaunchKernelGGL(chunk_kernel, dim3(NB * nc2), dim3(256), 0, stream, ks, vs, C2);
    hipLaunchKernelGGL(combine_kernel, dim3(NB), dim3(256), 0, stream,
                       ks, vs, M, M2, nc2, C2 * 64);

    hipLaunchKernelGGL(out_kernel, dim3(NB), dim3(128), 0, stream,
                       M2, ql, Wout, bout, (float*)d_out);
}

// Round 3
// 1016.632 us; speedup vs baseline: 2.6754x; 1.3797x over previous
//
#include <hip/hip_runtime.h>

#define H64 64
#define SEQL 4096
#define NB 64
#define TOK 32

// ---------------------------------------------------------------------------
// Encoder: embed -> FF(relu) -> residual -> LayerNorm -> k (l2norm), v, q, qlast
// One block = 32 tokens (never straddles a batch: 4096 % 32 == 0).
// ---------------------------------------------------------------------------
__global__ __launch_bounds__(256) void encoder_kernel(
    const int* __restrict__ x, const float* __restrict__ embed,
    const float* __restrict__ W1, const float* __restrict__ b1,
    const float* __restrict__ W2, const float* __restrict__ b2,
    const float* __restrict__ ln_g, const float* __restrict__ ln_b,
    const float* __restrict__ Wk, const float* __restrict__ Wv,
    const float* __restrict__ Wq, const float* __restrict__ Wattn,
    float* __restrict__ ks, float* __restrict__ vs,
    float* __restrict__ qbuf, float* __restrict__ qlast)
{
    __shared__ __align__(16) float sW[128 * 65];   // W1T[64][129] / W2T[128][65] / WT[64][65]
    __shared__ __align__(16) float sZT[64 * 36];   // h / hidden, transposed [i][t]
    __shared__ __align__(16) float sFT[128 * 36];  // ff1, transposed [p][t]
    __shared__ float sb1[128], sb2[64], sg[64], sbt[64];

    const int tid = threadIdx.x;
    const size_t g0 = (size_t)blockIdx.x * TOK;
    const int b = (int)(g0 >> 12);
    const int l0 = (int)(g0 & (SEQL - 1));

    if (tid < 128) sb1[tid] = b1[tid];
    else if (tid < 192) sb2[tid - 128] = b2[tid - 128];
    else { sg[tid - 192] = ln_g[tid - 192]; sbt[tid - 192] = ln_b[tid - 192]; }

    // h
    for (int idx = tid; idx < TOK * 64; idx += 256) {
        int t = idx >> 6, i = idx & 63;
        sZT[i * 36 + t] = embed[(size_t)x[g0 + t] * 64 + i];
    }
    // W1T[i][j] = W1[j][i]
    for (int idx = tid; idx < 128 * 64; idx += 256) {
        int j = idx >> 6, i = idx & 63;
        sW[i * 129 + j] = W1[idx];
    }
    __syncthreads();

    // ff1 = relu(h @ W1^T + b1), stored transposed
    {
        const int j = tid & 127, t0 = (tid >> 7) * 16;
        float acc[16];
#pragma unroll
        for (int t = 0; t < 16; ++t) acc[t] = sb1[j];
        for (int i = 0; i < 64; ++i) {
            float w = sW[i * 129 + j];
            const float4* hp = reinterpret_cast<const float4*>(&sZT[i * 36 + t0]);
            float4 h0 = hp[0], h1 = hp[1], h2 = hp[2], h3 = hp[3];
            acc[0] = fmaf(w, h0.x, acc[0]);  acc[1] = fmaf(w, h0.y, acc[1]);
            acc[2] = fmaf(w, h0.z, acc[2]);  acc[3] = fmaf(w, h0.w, acc[3]);
            acc[4] = fmaf(w, h1.x, acc[4]);  acc[5] = fmaf(w, h1.y, acc[5]);
            acc[6] = fmaf(w, h1.z, acc[6]);  acc[7] = fmaf(w, h1.w, acc[7]);
            acc[8] = fmaf(w, h2.x, acc[8]);  acc[9] = fmaf(w, h2.y, acc[9]);
            acc[10] = fmaf(w, h2.z, acc[10]); acc[11] = fmaf(w, h2.w, acc[11]);
            acc[12] = fmaf(w, h3.x, acc[12]); acc[13] = fmaf(w, h3.y, acc[13]);
            acc[14] = fmaf(w, h3.z, acc[14]); acc[15] = fmaf(w, h3.w, acc[15]);
        }
#pragma unroll
        for (int t = 0; t < 16; ++t) sFT[j * 36 + t0 + t] = fmaxf(acc[t], 0.f);
    }
    __syncthreads();

    // W2T[p][i] = W2[i][p]
    for (int idx = tid; idx < 64 * 128; idx += 256) {
        int i = idx >> 7, p = idx & 127;
        sW[p * 65 + i] = W2[idx];
    }
    __syncthreads();

    // ff2 + residual + LayerNorm (wave = 8 tokens, lane = channel i)
    {
        const int i = tid & 63, t0 = (tid >> 6) * 8;
        float acc[8];
#pragma unroll
        for (int t = 0; t < 8; ++t) acc[t] = sb2[i];
        for (int p = 0; p < 128; ++p) {
            float w = sW[p * 65 + i];
            const float4* fp = reinterpret_cast<const float4*>(&sFT[p * 36 + t0]);
            float4 f0 = fp[0], f1 = fp[1];
            acc[0] = fmaf(w, f0.x, acc[0]); acc[1] = fmaf(w, f0.y, acc[1]);
            acc[2] = fmaf(w, f0.z, acc[2]); acc[3] = fmaf(w, f0.w, acc[3]);
            acc[4] = fmaf(w, f1.x, acc[4]); acc[5] = fmaf(w, f1.y, acc[5]);
            acc[6] = fmaf(w, f1.z, acc[6]); acc[7] = fmaf(w, f1.w, acc[7]);
        }
#pragma unroll
        for (int t = 0; t < 8; ++t) {
            float z = sZT[i * 36 + t0 + t] + acc[t];
            float s = z, ss = z * z;
            for (int off = 32; off; off >>= 1) {
                s += __shfl_xor(s, off);
                ss += __shfl_xor(ss, off);
            }
            float mu = s * 0.015625f;
            float var = ss * 0.015625f - mu * mu;
            float inv = rsqrtf(var + 1e-5f);
            sZT[i * 36 + t0 + t] = (z - mu) * inv * sg[i] + sbt[i];
        }
    }
    __syncthreads();

    // ---- k projection (+ l2norm) ----
    for (int idx = tid; idx < 64 * 64; idx += 256) {
        int j = idx >> 6, i = idx & 63;
        sW[i * 65 + j] = Wk[idx];
    }
    __syncthreads();
    {
        const int j = tid & 63, t0 = (tid >> 6) * 8;
        float acc[8] = {0, 0, 0, 0, 0, 0, 0, 0};
        for (int i = 0; i < 64; ++i) {
            float w = sW[i * 65 + j];
            const float4* hp = reinterpret_cast<const float4*>(&sZT[i * 36 + t0]);
            float4 h0 = hp[0], h1 = hp[1];
            acc[0] = fmaf(w, h0.x, acc[0]); acc[1] = fmaf(w, h0.y, acc[1]);
            acc[2] = fmaf(w, h0.z, acc[2]); acc[3] = fmaf(w, h0.w, acc[3]);
            acc[4] = fmaf(w, h1.x, acc[4]); acc[5] = fmaf(w, h1.y, acc[5]);
            acc[6] = fmaf(w, h1.z, acc[6]); acc[7] = fmaf(w, h1.w, acc[7]);
        }
#pragma unroll
        for (int t = 0; t < 8; ++t) {
            float ssq = acc[t] * acc[t];
            for (int off = 32; off; off >>= 1) ssq += __shfl_xor(ssq, off);
            float n = sqrtf(ssq);
            float scale = 1.f / fmaxf(n, 1e-12f);
            ks[(g0 + t0 + t) * 64 + j] = acc[t] * scale;
        }
    }
    __syncthreads();

    // ---- v projection ----
    for (int idx = tid; idx < 64 * 64; idx += 256) {
        int j = idx >> 6, i = idx & 63;
        sW[i * 65 + j] = Wv[idx];
    }
    __syncthreads();
    {
        const int j = tid & 63, t0 = (tid >> 6) * 8;
        float acc[8] = {0, 0, 0, 0, 0, 0, 0, 0};
        for (int i = 0; i < 64; ++i) {
            float w = sW[i * 65 + j];
            const float4* hp = reinterpret_cast<const float4*>(&sZT[i * 36 + t0]);
            float4 h0 = hp[0], h1 = hp[1];
            acc[0] = fmaf(w, h0.x, acc[0]); acc[1] = fmaf(w, h0.y, acc[1]);
            acc[2] = fmaf(w, h0.z, acc[2]); acc[3] = fmaf(w, h0.w, acc[3]);
            acc[4] = fmaf(w, h1.x, acc[4]); acc[5] = fmaf(w, h1.y, acc[5]);
            acc[6] = fmaf(w, h1.z, acc[6]); acc[7] = fmaf(w, h1.w, acc[7]);
        }
#pragma unroll
        for (int t = 0; t < 8; ++t) vs[(g0 + t0 + t) * 64 + j] = acc[t];
    }
    __syncthreads();

    // ---- q projection (first half only) ----
    if (l0 < 2048) {
        for (int idx = tid; idx < 64 * 64; idx += 256) {
            int j = idx >> 6, i = idx & 63;
            sW[i * 65 + j] = Wattn[idx];
        }
        __syncthreads();
        const int j = tid & 63, t0 = (tid >> 6) * 8;
        float acc[8] = {0, 0, 0, 0, 0, 0, 0, 0};
        for (int i = 0; i < 64; ++i) {
            float w = sW[i * 65 + j];
            const float4* hp = reinterpret_cast<const float4*>(&sZT[i * 36 + t0]);
            float4 h0 = hp[0], h1 = hp[1];
            acc[0] = fmaf(w, h0.x, acc[0]); acc[1] = fmaf(w, h0.y, acc[1]);
            acc[2] = fmaf(w, h0.z, acc[2]); acc[3] = fmaf(w, h0.w, acc[3]);
            acc[4] = fmaf(w, h1.x, acc[4]); acc[5] = fmaf(w, h1.y, acc[5]);
            acc[6] = fmaf(w, h1.z, acc[6]); acc[7] = fmaf(w, h1.w, acc[7]);
        }
#pragma unroll
        for (int t = 0; t < 8; ++t)
            qbuf[((size_t)b * 2048 + l0 + t0 + t) * 64 + j] = acc[t];
        __syncthreads();
    }

    // ---- q_last (only the last block of each batch) ----
    if (l0 == SEQL - TOK) {
        for (int idx = tid; idx < 64 * 64; idx += 256) {
            int j = idx >> 6, i = idx & 63;
            sW[i * 65 + j] = Wq[idx];
        }
        __syncthreads();
        const int j = tid & 63, wv = tid >> 6;
        if (wv == 3) {
            float a = 0.f;
            for (int i = 0; i < 64; ++i) a = fmaf(sW[i * 65 + j], sZT[i * 36 + 31], a);
            qlast[b * 64 + j] = a;
        }
    }
}

// ---------------------------------------------------------------------------
// Chunked delta scan, phase A (unchanged from round 2).
// ---------------------------------------------------------------------------
#define STEP2(K0, K1, K2, K3, V)                                                \
    do {                                                                        \
        float dp0 = fmaf(p[0], K0.x, fmaf(p[1], K0.y, fmaf(p[2], K0.z, p[3] * K0.w))); \
        float dp1 = fmaf(p[4], K1.x, fmaf(p[5], K1.y, fmaf(p[6], K1.z, p[7] * K1.w))); \
        float dp2 = fmaf(p[8], K2.x, fmaf(p[9], K2.y, fmaf(p[10], K2.z, p[11] * K2.w))); \
        float dp3 = fmaf(p[12], K3.x, fmaf(p[13], K3.y, fmaf(p[14], K3.z, p[15] * K3.w))); \
        float dq0 = fmaf(q[0], K0.x, fmaf(q[1], K0.y, fmaf(q[2], K0.z, q[3] * K0.w))); \
        float dq1 = fmaf(q[4], K1.x, fmaf(q[5], K1.y, fmaf(q[6], K1.z, q[7] * K1.w))); \
        float dq2 = fmaf(q[8], K2.x, fmaf(q[9], K2.y, fmaf(q[10], K2.z, q[11] * K2.w))); \
        float dq3 = fmaf(q[12], K3.x, fmaf(q[13], K3.y, fmaf(q[14], K3.z, q[15] * K3.w))); \
        float ddp = (dp0 + dp1) + (dp2 + dp3);                                  \
        float ddq = (dq0 + dq1) + (dq2 + dq3);                                  \
        ddp += __shfl_xor(ddp, 1);  ddq += __shfl_xor(ddq, 1);                  \
        ddp += __shfl_xor(ddp, 2);  ddq += __shfl_xor(ddq, 2);                  \
        float up = -ddp;                                                        \
        float uq = V - ddq;                                                     \
        p[0] = fmaf(up, K0.x, p[0]);   q[0] = fmaf(uq, K0.x, q[0]);             \
        p[1] = fmaf(up, K0.y, p[1]);   q[1] = fmaf(uq, K0.y, q[1]);             \
        p[2] = fmaf(up, K0.z, p[2]);   q[2] = fmaf(uq, K0.z, q[2]);             \
        p[3] = fmaf(up, K0.w, p[3]);   q[3] = fmaf(uq, K0.w, q[3]);             \
        p[4] = fmaf(up, K1.x, p[4]);   q[4] = fmaf(uq, K1.x, q[4]);             \
        p[5] = fmaf(up, K1.y, p[5]);   q[5] = fmaf(uq, K1.y, q[5]);             \
        p[6] = fmaf(up, K1.z, p[6]);   q[6] = fmaf(uq, K1.z, q[6]);             \
        p[7] = fmaf(up, K1.w, p[7]);   q[7] = fmaf(uq, K1.w, q[7]);             \
        p[8] = fmaf(up, K2.x, p[8]);   q[8] = fmaf(uq, K2.x, q[8]);             \
        p[9] = fmaf(up, K2.y, p[9]);   q[9] = fmaf(uq, K2.y, q[9]);             \
        p[10] = fmaf(up, K2.z, p[10]); q[10] = fmaf(uq, K2.z, q[10]);           \
        p[11] = fmaf(up, K2.w, p[11]); q[11] = fmaf(uq, K2.w, q[11]);           \
        p[12] = fmaf(up, K3.x, p[12]); q[12] = fmaf(uq, K3.x, q[12]);           \
        p[13] = fmaf(up, K3.y, p[13]); q[13] = fmaf(uq, K3.y, q[13]);           \
        p[14] = fmaf(up, K3.z, p[14]); q[14] = fmaf(uq, K3.z, q[14]);           \
        p[15] = fmaf(up, K3.w, p[15]); q[15] = fmaf(uq, K3.w, q[15]);           \
    } while (0)

__global__ __launch_bounds__(256) void chunk_kernel(
    float* __restrict__ ksb, float* __restrict__ vsb, int C)
{
    const int job = blockIdx.x;
    const int tid = threadIdx.x;
    const int r = tid >> 2;
    const int c0 = (tid & 3) * 16;
    float* kc = ksb + (size_t)job * C * 64;
    float* vc = vsb + (size_t)job * C * 64;

    float p[16], q[16];
#pragma unroll
    for (int j = 0; j < 16; ++j) { p[j] = (c0 + j == r) ? 1.f : 0.f; q[j] = 0.f; }

    const float* kb = kc + c0;
    const float* vp = vc + r;

    float4 a0, a1, a2, a3, e0, e1, e2, e3;
    float va, ve;
    {
        const float4* kp = reinterpret_cast<const float4*>(kb);
        a0 = kp[0]; a1 = kp[1]; a2 = kp[2]; a3 = kp[3];
        va = vp[0];
    }
    for (int t = 0; t < C; t += 2) {
        {
            const float4* kp = reinterpret_cast<const float4*>(kb + (size_t)(t + 1) * 64);
            e0 = kp[0]; e1 = kp[1]; e2 = kp[2]; e3 = kp[3];
            ve = vp[(size_t)(t + 1) * 64];
        }
        STEP2(a0, a1, a2, a3, va);
        if (t + 2 < C) {
            const float4* kp = reinterpret_cast<const float4*>(kb + (size_t)(t + 2) * 64);
            a0 = kp[0]; a1 = kp[1]; a2 = kp[2]; a3 = kp[3];
            va = vp[(size_t)(t + 2) * 64];
        }
        STEP2(e0, e1, e2, e3, ve);
    }

    float4* po = reinterpret_cast<float4*>(kc + r * 64 + c0);
    po[0] = make_float4(p[0], p[1], p[2], p[3]);
    po[1] = make_float4(p[4], p[5], p[6], p[7]);
    po[2] = make_float4(p[8], p[9], p[10], p[11]);
    po[3] = make_float4(p[12], p[13], p[14], p[15]);
    float4* qo = reinterpret_cast<float4*>(vc + r * 64 + c0);
    qo[0] = make_float4(q[0], q[1], q[2], q[3]);
    qo[1] = make_float4(q[4], q[5], q[6], q[7]);
    qo[2] = make_float4(q[8], q[9], q[10], q[11]);
    qo[3] = make_float4(q[12], q[13], q[14], q[15]);
}

// ---------------------------------------------------------------------------
// Chunked delta scan, phase B (unchanged from round 2).
// ---------------------------------------------------------------------------
__global__ __launch_bounds__(256) void combine_kernel(
    const float* __restrict__ Pb, const float* __restrict__ Qb,
    const float* __restrict__ Min, float* __restrict__ Mout,
    int nc, int chunk_stride)
{
    __shared__ __align__(16) float sM[2][64 * 68];
    __shared__ __align__(16) float sP[2][64 * 64];
    const int b = blockIdx.x;
    const int tid = threadIdx.x;
    const int r = tid >> 2;
    const int j0 = (tid & 3) * 16;

    if (Min) {
        const float4* mi = reinterpret_cast<const float4*>(Min + ((size_t)b * 64 + r) * 64 + j0);
        float4* mo = reinterpret_cast<float4*>(&sM[0][r * 68 + j0]);
#pragma unroll
        for (int u = 0; u < 4; ++u) mo[u] = mi[u];
    } else {
#pragma unroll
        for (int u = 0; u < 16; ++u) sM[0][r * 68 + j0 + u] = 0.f;
    }
    {
        const float4* g = reinterpret_cast<const float4*>(Pb + (size_t)b * nc * chunk_stride);
        float4* s = reinterpret_cast<float4*>(sP[0]);
        for (int i = tid; i < 1024; i += 256) s[i] = g[i];
    }
    __syncthreads();

    int cur = 0;
    for (int c = 0; c < nc; ++c) {
        const size_t cbase = (size_t)(b * nc + c) * chunk_stride;
        float4 rp0, rp1, rp2, rp3;
        if (c + 1 < nc) {
            const float4* g = reinterpret_cast<const float4*>(Pb + cbase + chunk_stride);
            rp0 = g[tid]; rp1 = g[tid + 256]; rp2 = g[tid + 512]; rp3 = g[tid + 768];
        }
        float4 rq0, rq1, rq2, rq3;
        {
            const float4* gq = reinterpret_cast<const float4*>(Qb + cbase + r * 64 + j0);
            rq0 = gq[0]; rq1 = gq[1]; rq2 = gq[2]; rq3 = gq[3];
        }
        float acc[16];
#pragma unroll
        for (int u = 0; u < 16; ++u) acc[u] = 0.f;
        const float* Mrow = &sM[cur][r * 68];
        const float* Pl = sP[c & 1];
#pragma unroll
        for (int mg = 0; mg < 16; ++mg) {
            float4 a = *reinterpret_cast<const float4*>(Mrow + mg * 4);
#pragma unroll
            for (int e2 = 0; e2 < 4; ++e2) {
                float am = (e2 == 0) ? a.x : (e2 == 1) ? a.y : (e2 == 2) ? a.z : a.w;
                const float4* pr = reinterpret_cast<const float4*>(Pl + (mg * 4 + e2) * 64 + j0);
                float4 p0 = pr[0], p1 = pr[1], p2 = pr[2], p3 = pr[3];
                acc[0] = fmaf(am, p0.x, acc[0]);  acc[1] = fmaf(am, p0.y, acc[1]);
                acc[2] = fmaf(am, p0.z, acc[2]);  acc[3] = fmaf(am, p0.w, acc[3]);
                acc[4] = fmaf(am, p1.x, acc[4]);  acc[5] = fmaf(am, p1.y, acc[5]);
                acc[6] = fmaf(am, p1.z, acc[6]);  acc[7] = fmaf(am, p1.w, acc[7]);
                acc[8] = fmaf(am, p2.x, acc[8]);  acc[9] = fmaf(am, p2.y, acc[9]);
                acc[10] = fmaf(am, p2.z, acc[10]); acc[11] = fmaf(am, p2.w, acc[11]);
                acc[12] = fmaf(am, p3.x, acc[12]); acc[13] = fmaf(am, p3.y, acc[13]);
                acc[14] = fmaf(am, p3.z, acc[14]); acc[15] = fmaf(am, p3.w, acc[15]);
            }
        }
        const int nxt = cur ^ 1;
        float* om = &sM[nxt][r * 68 + j0];
        om[0] = acc[0] + rq0.x;  om[1] = acc[1] + rq0.y;
        om[2] = acc[2] + rq0.z;  om[3] = acc[3] + rq0.w;
        om[4] = acc[4] + rq1.x;  om[5] = acc[5] + rq1.y;
        om[6] = acc[6] + rq1.z;  om[7] = acc[7] + rq1.w;
        om[8] = acc[8] + rq2.x;  om[9] = acc[9] + rq2.y;
        om[10] = acc[10] + rq2.z; om[11] = acc[11] + rq2.w;
        om[12] = acc[12] + rq3.x; om[13] = acc[13] + rq3.y;
        om[14] = acc[14] + rq3.z; om[15] = acc[15] + rq3.w;
        if (c + 1 < nc) {
            float4* s = reinterpret_cast<float4*>(sP[(c + 1) & 1]);
            s[tid] = rp0; s[tid + 256] = rp1; s[tid + 512] = rp2; s[tid + 768] = rp3;
        }
        __syncthreads();
        cur = nxt;
    }

    float4* mo = reinterpret_cast<float4*>(Mout + ((size_t)b * 64 + r) * 64 + j0);
    const float* fm = &sM[cur][r * 68 + j0];
    mo[0] = make_float4(fm[0], fm[1], fm[2], fm[3]);
    mo[1] = make_float4(fm[4], fm[5], fm[6], fm[7]);
    mo[2] = make_float4(fm[8], fm[9], fm[10], fm[11]);
    mo[3] = make_float4(fm[12], fm[13], fm[14], fm[15]);
}

// ---------------------------------------------------------------------------
// Attention read + second k/v projection, v2: LDS-tile GEMM style.
// Block = 32 tokens. All GEMM phases: reduction dim = conflict-free scalar
// LDS read (stride 65: both row AND column access of sM are conflict-free
// since 65 % 32 == 1), token dim = same-address float4 broadcast (stride 36).
// Cross-lane ops reduced to independent butterflies (softmax, l2norm).
// ---------------------------------------------------------------------------
__global__ __launch_bounds__(256) void attn_kernel(
    const float* __restrict__ qg, const float* __restrict__ Mbuf,
    const float* __restrict__ Wk, const float* __restrict__ Wv,
    float* __restrict__ ks2, float* __restrict__ vs2)
{
    __shared__ __align__(16) float sM[64 * 65];
    __shared__ __align__(16) float sWkT[64 * 65];
    __shared__ __align__(16) float sWvT[64 * 65];
    __shared__ __align__(16) float sA[64 * 36];   // qT -> ctxT  [h][t]
    __shared__ __align__(16) float sB[64 * 36];   // pT          [k][t]

    const int b = blockIdx.y;
    const int tile0 = blockIdx.x * 32;
    const int tid = threadIdx.x;
    const int lane = tid & 63;
    const int t0 = (tid >> 6) * 8;
    const size_t qbase = (size_t)b * 2048 + tile0;

    // stage M (row-major), WkT, WvT
    for (int idx = tid; idx < 4096; idx += 256) {
        int rr = idx >> 6, cc = idx & 63;
        sM[rr * 65 + cc] = Mbuf[(size_t)b * 4096 + idx];
        sWkT[cc * 65 + rr] = Wk[idx];
        sWvT[cc * 65 + rr] = Wv[idx];
    }
    // stage qT [h][t]: coalesced float4 global reads, scalar LDS scatter
    for (int it = tid; it < 512; it += 256) {
        int hg = it & 15, t = it >> 4;
        float4 qv = *reinterpret_cast<const float4*>(&qg[(qbase + t) * 64 + hg * 4]);
        sA[(hg * 4 + 0) * 36 + t] = qv.x;
        sA[(hg * 4 + 1) * 36 + t] = qv.y;
        sA[(hg * 4 + 2) * 36 + t] = qv.z;
        sA[(hg * 4 + 3) * 36 + t] = qv.w;
    }
    __syncthreads();

    // phase 1: scores s[t][k=lane] = sum_h q[t][h] * M[h][k]
    float acc[8];
#pragma unroll
    for (int u = 0; u < 8; ++u) acc[u] = 0.f;
    for (int h = 0; h < 64; ++h) {
        float w = sM[h * 65 + lane];
        const float4* qp = reinterpret_cast<const float4*>(&sA[h * 36 + t0]);
        float4 q0 = qp[0], q1 = qp[1];
        acc[0] = fmaf(w, q0.x, acc[0]); acc[1] = fmaf(w, q0.y, acc[1]);
        acc[2] = fmaf(w, q0.z, acc[2]); acc[3] = fmaf(w, q0.w, acc[3]);
        acc[4] = fmaf(w, q1.x, acc[4]); acc[5] = fmaf(w, q1.y, acc[5]);
        acc[6] = fmaf(w, q1.z, acc[6]); acc[7] = fmaf(w, q1.w, acc[7]);
    }

    // softmax across lanes (k) per token, independent butterflies
#pragma unroll
    for (int u = 0; u < 8; ++u) {
        float sv = acc[u] * 0.125f;
        float mx = sv;
        for (int off = 32; off; off >>= 1) mx = fmaxf(mx, __shfl_xor(mx, off));
        float e = __expf(sv - mx);
        float sm = e;
        for (int off = 32; off; off >>= 1) sm += __shfl_xor(sm, off);
        acc[u] = e / sm;
    }
    // store pT [k=lane][t]
#pragma unroll
    for (int u = 0; u < 8; ++u) sB[lane * 36 + t0 + u] = acc[u];
    __syncthreads();

    // phase 2: ctx[t][h=lane] = sum_k p[t][k] * M[h][k]  (row read of sM)
#pragma unroll
    for (int u = 0; u < 8; ++u) acc[u] = 0.f;
    for (int k = 0; k < 64; ++k) {
        float m = sM[lane * 65 + k];
        const float4* pp = reinterpret_cast<const float4*>(&sB[k * 36 + t0]);
        float4 p0 = pp[0], p1 = pp[1];
        acc[0] = fmaf(m, p0.x, acc[0]); acc[1] = fmaf(m, p0.y, acc[1]);
        acc[2] = fmaf(m, p0.z, acc[2]); acc[3] = fmaf(m, p0.w, acc[3]);
        acc[4] = fmaf(m, p1.x, acc[4]); acc[5] = fmaf(m, p1.y, acc[5]);
        acc[6] = fmaf(m, p1.z, acc[6]); acc[7] = fmaf(m, p1.w, acc[7]);
    }
    // store ctxT [h=lane][t] (overwrites qT; all sA reads done pre-barrier)
#pragma unroll
    for (int u = 0; u < 8; ++u) sA[lane * 36 + t0 + u] = acc[u];
    __syncthreads();

    // phase 3: k2[t][j=lane], v2[t][j=lane] fused
    float ak[8], av[8];
#pragma unroll
    for (int u = 0; u < 8; ++u) { ak[u] = 0.f; av[u] = 0.f; }
    for (int h = 0; h < 64; ++h) {
        float wk = sWkT[h * 65 + lane];
        float wv = sWvT[h * 65 + lane];
        const float4* cp = reinterpret_cast<const float4*>(&sA[h * 36 + t0]);
        float4 c0 = cp[0], c1 = cp[1];
        ak[0] = fmaf(wk, c0.x, ak[0]); av[0] = fmaf(wv, c0.x, av[0]);
        ak[1] = fmaf(wk, c0.y, ak[1]); av[1] = fmaf(wv, c0.y, av[1]);
        ak[2] = fmaf(wk, c0.z, ak[2]); av[2] = fmaf(wv, c0.z, av[2]);
        ak[3] = fmaf(wk, c0.w, ak[3]); av[3] = fmaf(wv, c0.w, av[3]);
        ak[4] = fmaf(wk, c1.x, ak[4]); av[4] = fmaf(wv, c1.x, av[4]);
        ak[5] = fmaf(wk, c1.y, ak[5]); av[5] = fmaf(wv, c1.y, av[5]);
        ak[6] = fmaf(wk, c1.z, ak[6]); av[6] = fmaf(wv, c1.z, av[6]);
        ak[7] = fmaf(wk, c1.w, ak[7]); av[7] = fmaf(wv, c1.w, av[7]);
    }
    // l2norm across lanes (j) per token + store
#pragma unroll
    for (int u = 0; u < 8; ++u) {
        float ssq = ak[u] * ak[u];
        for (int off = 32; off; off >>= 1) ssq += __shfl_xor(ssq, off);
        float n = sqrtf(ssq);
        float sc = 1.f / fmaxf(n, 1e-12f);
        const size_t o = (qbase + t0 + u) * 64 + lane;
        ks2[o] = ak[u] * sc;
        vs2[o] = av[u];
    }
}

// ---------------------------------------------------------------------------
// Output: read = M2 @ q_last; out = read @ Wout^T + bout
// ---------------------------------------------------------------------------
__global__ __launch_bounds__(128) void out_kernel(
    const float* __restrict__ M2, const float* __restrict__ qlast,
    const float* __restrict__ Wout, const float* __restrict__ bout,
    float* __restrict__ out)
{
    const int b = blockIdx.x;
    const int tid = threadIdx.x;
    __shared__ float sq[64], sread[64];
    if (tid < 64) sq[tid] = qlast[b * 64 + tid];
    __syncthreads();
    if (tid < 64) {
        const float* Mr = M2 + ((size_t)b * 64 + tid) * 64;
        float acc = 0.f;
        for (int j = 0; j < 64; ++j) acc = fmaf(Mr[j], sq[j], acc);
        sread[tid] = acc;
    }
    __syncthreads();
    float acc = bout[tid];
    for (int h = 0; h < 64; ++h) acc = fmaf(Wout[tid * 64 + h], sread[h], acc);
    out[b * 128 + tid] = acc;
}

// ---------------------------------------------------------------------------
extern "C" void kernel_launch(void* const* d_in, const int* in_sizes, int n_in,
                              void* d_out, int out_size, void* d_ws, size_t ws_size,
                              hipStream_t stream)
{
    const int* x        = (const int*)d_in[0];
    const float* embed  = (const float*)d_in[1];
    const float* W1     = (const float*)d_in[2];
    const float* b1     = (const float*)d_in[3];
    const float* W2     = (const float*)d_in[4];
    const float* b2     = (const float*)d_in[5];
    const float* ln_g   = (const float*)d_in[6];
    const float* ln_b   = (const float*)d_in[7];
    const float* Wk     = (const float*)d_in[8];
    const float* Wv     = (const float*)d_in[9];
    const float* Wq     = (const float*)d_in[10];
    const float* Wattn  = (const float*)d_in[11];
    const float* Wout   = (const float*)d_in[12];
    const float* bout   = (const float*)d_in[13];

    // workspace layout (floats): ks | vs | q | qlast | M | M2
    float* ws = (float*)d_ws;
    float* ks = ws;
    float* vs = ks + (size_t)NB * SEQL * 64;
    float* qb = vs + (size_t)NB * SEQL * 64;
    float* ql = qb + (size_t)NB * 2048 * 64;
    float* M  = ql + (size_t)NB * 64;
    float* M2 = M + (size_t)NB * 64 * 64;
    if (ws_size < (size_t)(M2 + (size_t)NB * 64 * 64 - ws) * sizeof(float)) return;

    hipLaunchKernelGGL(encoder_kernel, dim3((NB * SEQL) / TOK), dim3(256), 0, stream,
                       x, embed, W1, b1, W2, b2, ln_g, ln_b, Wk, Wv, Wq, Wattn,
                       ks, vs, qb, ql);

    // scan 1: L=4096, C=256 -> 16 chunks/batch, 1024 parallel chunk jobs
    const int C1 = 256, nc1 = SEQL / C1;
    hipLaunchKernelGGL(chunk_kernel, dim3(NB * nc1), dim3(256), 0, stream, ks, vs, C1);
    hipLaunchKernelGGL(combine_kernel, dim3(NB), dim3(256), 0, stream,
                       ks, vs, (const float*)nullptr, M, nc1, C1 * 64);

    // attention + second k/v projection (ks2/vs2 reuse ks/vs)
    hipLaunchKernelGGL(attn_kernel, dim3(64, NB), dim3(256), 0, stream,
                       qb, M, Wk, Wv, ks, vs);

    // scan 2: L=2048, C=128 -> 16 chunks/batch, 1024 parallel chunk jobs
    const int C2 = 128, nc2 = 2048 / C2;
    hipLaunchKernelGGL(chunk_kernel, dim3(NB * nc2), dim3(256), 0, stream, ks, vs, C2);
    hipLaunchKernelGGL(combine_kernel, dim3(NB), dim3(256), 0, stream,
                       ks, vs, M, M2, nc2, C2 * 64);

    hipLaunchKernelGGL(out_kernel, dim3(NB), dim3(128), 0, stream,
                       M2, ql, Wout, bout, (float*)d_out);
}